// Round 1
// baseline (719.868 us; speedup 1.0000x reference)
//
#include <hip/hip_runtime.h>
#include <math.h>

#define TPB 256
#define CHUNKS_PER_BLOCK (TPB * 4)   // 4 int4-label chunks per thread

typedef float fx4 __attribute__((ext_vector_type(4)));
typedef int   ix4 __attribute__((ext_vector_type(4)));

// ws layout:
//   [0, 4)                     : uint ticket   (zeroed each launch via 64B hipMemsetAsync)
//   [256, 256 + 8*nparts)      : double-bits ce_part  (written as ull, release/agent)
//   [.. + 8*nparts)            : ull cnt_part (4 x 16-bit packed fields)
// Partials need no zero-init: every block writes its slot before any block reads it
// (ordering established by the acq_rel ticket).

__device__ __forceinline__ void proc(float o0, float o1, int l,
                                     float& ce, unsigned long long& cnt) {
    // d = o0-o1; pred = (d<0); ce += softplus(l? d : -d)
    const float d = o0 - o1;
    ce += fmaxf(l ? d : -d, 0.0f) + __logf(1.0f + __expf(-fabsf(d)));
    cnt += 1ull << ((((l << 1) | (d < 0.0f ? 1 : 0))) << 4);  // field = label*2+pred
}

__global__ __launch_bounds__(TPB) void detloss_fused(
    const fx4* __restrict__ out4,   // outputs as float4 (2 elements each)
    const ix4* __restrict__ lab4,   // labels as int4 (4 elements each)
    unsigned int* __restrict__ ticket,
    unsigned long long* __restrict__ ce_part,
    unsigned long long* __restrict__ cnt_part,
    float* __restrict__ out,
    int B, int nchunks, int nparts)
{
    float ce = 0.0f;
    unsigned long long cnt = 0ull;     // 4 x 16-bit fields (<=16 per field per thread)
    const int tid = threadIdx.x;
    const int g0 = blockIdx.x * CHUNKS_PER_BLOCK + tid;
    const int g1 = g0 + TPB, g2 = g1 + TPB, g3 = g2 + TPB;

    if (g3 < nchunks) {
        // fast path: all 12 loads issued up front, nontemporal (read-once stream)
        const ix4 lb0 = __builtin_nontemporal_load(lab4 + g0);
        const ix4 lb1 = __builtin_nontemporal_load(lab4 + g1);
        const ix4 lb2 = __builtin_nontemporal_load(lab4 + g2);
        const ix4 lb3 = __builtin_nontemporal_load(lab4 + g3);
        const fx4 a0 = __builtin_nontemporal_load(out4 + 2*g0);
        const fx4 b0 = __builtin_nontemporal_load(out4 + 2*g0 + 1);
        const fx4 a1 = __builtin_nontemporal_load(out4 + 2*g1);
        const fx4 b1 = __builtin_nontemporal_load(out4 + 2*g1 + 1);
        const fx4 a2 = __builtin_nontemporal_load(out4 + 2*g2);
        const fx4 b2 = __builtin_nontemporal_load(out4 + 2*g2 + 1);
        const fx4 a3 = __builtin_nontemporal_load(out4 + 2*g3);
        const fx4 b3 = __builtin_nontemporal_load(out4 + 2*g3 + 1);

        proc(a0.x,a0.y,lb0.x,ce,cnt); proc(a0.z,a0.w,lb0.y,ce,cnt);
        proc(b0.x,b0.y,lb0.z,ce,cnt); proc(b0.z,b0.w,lb0.w,ce,cnt);
        proc(a1.x,a1.y,lb1.x,ce,cnt); proc(a1.z,a1.w,lb1.y,ce,cnt);
        proc(b1.x,b1.y,lb1.z,ce,cnt); proc(b1.z,b1.w,lb1.w,ce,cnt);
        proc(a2.x,a2.y,lb2.x,ce,cnt); proc(a2.z,a2.w,lb2.y,ce,cnt);
        proc(b2.x,b2.y,lb2.z,ce,cnt); proc(b2.z,b2.w,lb2.w,ce,cnt);
        proc(a3.x,a3.y,lb3.x,ce,cnt); proc(a3.z,a3.w,lb3.y,ce,cnt);
        proc(b3.x,b3.y,lb3.z,ce,cnt); proc(b3.z,b3.w,lb3.w,ce,cnt);
    } else {
        // tail blocks (unused for B = 2^24): per-chunk guards
        #pragma unroll
        for (int k = 0; k < 4; ++k) {
            const int g = g0 + k * TPB;
            if (g < nchunks) {
                const ix4 lb = lab4[g];
                const fx4 a = out4[2*g], b = out4[2*g+1];
                proc(a.x,a.y,lb.x,ce,cnt); proc(a.z,a.w,lb.y,ce,cnt);
                proc(b.x,b.y,lb.z,ce,cnt); proc(b.z,b.w,lb.w,ce,cnt);
            }
        }
    }

    // wave (64-lane) shuffle reduction
    #pragma unroll
    for (int off = 32; off > 0; off >>= 1) {
        ce  += __shfl_down(ce, off);
        cnt += __shfl_down(cnt, off);
    }

    __shared__ float              s_ce[TPB / 64];
    __shared__ unsigned long long s_cnt[TPB / 64];
    __shared__ int                s_last;
    const int wave = tid >> 6;
    const int lane = tid & 63;
    if (lane == 0) { s_ce[wave] = ce; s_cnt[wave] = cnt; }
    __syncthreads();

    if (tid == 0) {
        float bce = 0.0f;
        unsigned long long bc = 0ull;   // block totals <= 4096/field, fits 16 bits
        #pragma unroll
        for (int w = 0; w < TPB / 64; ++w) { bce += s_ce[w]; bc += s_cnt[w]; }
        // release/agent stores: must reach the coherence point (per-XCD L2s are
        // NOT cross-coherent); the acq_rel ticket orders them for the last block.
        __hip_atomic_store(&ce_part[blockIdx.x],
                           (unsigned long long)__double_as_longlong((double)bce),
                           __ATOMIC_RELEASE, __HIP_MEMORY_SCOPE_AGENT);
        __hip_atomic_store(&cnt_part[blockIdx.x], bc,
                           __ATOMIC_RELEASE, __HIP_MEMORY_SCOPE_AGENT);
        const unsigned int old = __hip_atomic_fetch_add(ticket, 1u,
                           __ATOMIC_ACQ_REL, __HIP_MEMORY_SCOPE_AGENT);
        s_last = (old == (unsigned int)(nparts - 1));
    }
    __syncthreads();
    if (!s_last) return;

    // ---- last block only: final cross-block reduction (replaces 2nd kernel) ----
    double ced = 0.0;
    // unpack BEFORE cross-block summation (16-bit fields would overflow)
    unsigned int q0 = 0, q1 = 0, q2 = 0, q3 = 0;
    for (int s = tid; s < nparts; s += TPB) {
        const unsigned long long cb = __hip_atomic_load(&ce_part[s],
                               __ATOMIC_RELAXED, __HIP_MEMORY_SCOPE_AGENT);
        ced += __longlong_as_double((long long)cb);
        const unsigned long long c  = __hip_atomic_load(&cnt_part[s],
                               __ATOMIC_RELAXED, __HIP_MEMORY_SCOPE_AGENT);
        q0 += (unsigned int)( c        & 0xffffull);  // TN
        q1 += (unsigned int)((c >> 16) & 0xffffull);  // FP
        q2 += (unsigned int)((c >> 32) & 0xffffull);  // FN
        q3 += (unsigned int)( c >> 48);               // TP
    }

    #pragma unroll
    for (int off = 32; off > 0; off >>= 1) {
        ced += __shfl_down(ced, off);
        q0  += __shfl_down(q0, off);
        q1  += __shfl_down(q1, off);
        q2  += __shfl_down(q2, off);
        q3  += __shfl_down(q3, off);
    }

    __shared__ double       f_ce[TPB / 64];
    __shared__ unsigned int f_q[4][TPB / 64];
    if (lane == 0) {
        f_ce[wave] = ced;
        f_q[0][wave] = q0; f_q[1][wave] = q1; f_q[2][wave] = q2; f_q[3][wave] = q3;
    }
    __syncthreads();

    if (tid == 0) {
        double ceT = 0.0;
        unsigned int TNu = 0, FPu = 0, FNu = 0, TPu = 0;
        #pragma unroll
        for (int w = 0; w < TPB / 64; ++w) {
            ceT += f_ce[w];
            TNu += f_q[0][w]; FPu += f_q[1][w]; FNu += f_q[2][w]; TPu += f_q[3][w];
        }
        const double TN = (double)TNu, FP = (double)FPu,
                     FN = (double)FNu, TP = (double)TPu;
        const double invB = 1.0 / (double)B;
        const bool nonzero = (TP > 0.0) && (TN > 0.0) && (FP > 0.0) && (FN > 0.0);
        const double ratio = (TP / fmax(TP + FN, 1.0)) * (FP / fmax(FP + TN, 1.0));
        const double coeff = nonzero ? (-0.5 * log(sqrt(fmax(ratio, 1e-30)))) : 0.5;
        // N_CLASSES=2: M[pred,label]==1 only when pred=0 & label=1 => sum(CS) == FN
        out[0] = (float)(ceT * invB + coeff * FN * invB);
    }
}

extern "C" void kernel_launch(void* const* d_in, const int* in_sizes, int n_in,
                              void* d_out, int out_size, void* d_ws, size_t ws_size,
                              hipStream_t stream) {
    const float* outputs = (const float*)d_in[0];
    const int*   labels  = (const int*)d_in[1];
    const int B = in_sizes[1];

    const int nchunks = B / 4;                                   // B = 2^24
    const int nparts  = (nchunks + CHUNKS_PER_BLOCK - 1) / CHUNKS_PER_BLOCK;  // 4096

    unsigned int*       ticket   = (unsigned int*)d_ws;
    unsigned long long* ce_part  = (unsigned long long*)((char*)d_ws + 256);
    unsigned long long* cnt_part = ce_part + nparts;

    // ws is poisoned by the harness each iteration — ticket must start at 0.
    hipMemsetAsync(d_ws, 0, 64, stream);

    detloss_fused<<<nparts, TPB, 0, stream>>>(
        (const fx4*)outputs, (const ix4*)labels,
        ticket, ce_part, cnt_part, (float*)d_out, B, nchunks, nparts);
}

// Round 2
// 218.843 us; speedup vs baseline: 3.2894x; 3.2894x over previous
//
#include <hip/hip_runtime.h>
#include <math.h>

#define TPB 256
#define GROUPS 4                         // 4 x (4 int4-chunks/thread) groups
#define CPB (TPB * 4 * GROUPS)           // 4096 chunks per block -> 1024 blocks

typedef float fx4 __attribute__((ext_vector_type(4)));
typedef int   ix4 __attribute__((ext_vector_type(4)));

// ws layout:
//   [0, 4)                : uint ticket (zeroed each launch via 64B hipMemsetAsync)
//   [256, 256+8*nparts)   : double-bits ce_part (relaxed agent atomic stores, sc1)
//   [.. +8*nparts)        : ull cnt_part (4 x 16-bit packed fields)
//
// MEMORY-MODEL NOTE (round-1 post-mortem): agent-scope RELEASE/ACQUIRE on gfx950
// lower to buffer_wbl2 / buffer_inv (whole-L2 writeback/invalidate) because per-XCD
// L2s are not coherent. 4096 of those serialized the machine (548us @ 2.4% BW).
// Therefore: RELAXED-only atomics (plain sc1 ops, visible at the MALL, no cache
// maintenance) + one inline-asm s_waitcnt vmcnt(0) for store->ticket ordering.

__device__ __forceinline__ void proc(float o0, float o1, int l,
                                     float& ce, unsigned long long& cnt) {
    // d = o0-o1; pred = (d<0); ce += softplus(l? d : -d)
    const float d = o0 - o1;
    ce += fmaxf(l ? d : -d, 0.0f) + __logf(1.0f + __expf(-fabsf(d)));
    cnt += 1ull << ((((l << 1) | (d < 0.0f ? 1 : 0))) << 4);  // field = label*2+pred
}

__global__ __launch_bounds__(TPB) void detloss_fused(
    const fx4* __restrict__ out4,   // outputs as float4 (2 elements each)
    const ix4* __restrict__ lab4,   // labels as int4 (4 elements each)
    unsigned int* __restrict__ ticket,
    unsigned long long* __restrict__ ce_part,
    unsigned long long* __restrict__ cnt_part,
    float* __restrict__ out,
    int B, int nchunks, int nparts)
{
    float ce = 0.0f;
    unsigned long long cnt = 0ull;  // 4 x 16-bit fields; <=64/field/thread, <=16384/block
    const int tid  = threadIdx.x;
    const int base = blockIdx.x * CPB;

    if (base + CPB <= nchunks) {
        #pragma unroll
        for (int grp = 0; grp < GROUPS; ++grp) {
            const int g0 = base + grp * (TPB * 4) + tid;
            const int g1 = g0 + TPB, g2 = g1 + TPB, g3 = g2 + TPB;
            // 12 loads issued up front, nontemporal (read-once stream)
            const ix4 lb0 = __builtin_nontemporal_load(lab4 + g0);
            const ix4 lb1 = __builtin_nontemporal_load(lab4 + g1);
            const ix4 lb2 = __builtin_nontemporal_load(lab4 + g2);
            const ix4 lb3 = __builtin_nontemporal_load(lab4 + g3);
            const fx4 a0 = __builtin_nontemporal_load(out4 + 2*g0);
            const fx4 b0 = __builtin_nontemporal_load(out4 + 2*g0 + 1);
            const fx4 a1 = __builtin_nontemporal_load(out4 + 2*g1);
            const fx4 b1 = __builtin_nontemporal_load(out4 + 2*g1 + 1);
            const fx4 a2 = __builtin_nontemporal_load(out4 + 2*g2);
            const fx4 b2 = __builtin_nontemporal_load(out4 + 2*g2 + 1);
            const fx4 a3 = __builtin_nontemporal_load(out4 + 2*g3);
            const fx4 b3 = __builtin_nontemporal_load(out4 + 2*g3 + 1);

            proc(a0.x,a0.y,lb0.x,ce,cnt); proc(a0.z,a0.w,lb0.y,ce,cnt);
            proc(b0.x,b0.y,lb0.z,ce,cnt); proc(b0.z,b0.w,lb0.w,ce,cnt);
            proc(a1.x,a1.y,lb1.x,ce,cnt); proc(a1.z,a1.w,lb1.y,ce,cnt);
            proc(b1.x,b1.y,lb1.z,ce,cnt); proc(b1.z,b1.w,lb1.w,ce,cnt);
            proc(a2.x,a2.y,lb2.x,ce,cnt); proc(a2.z,a2.w,lb2.y,ce,cnt);
            proc(b2.x,b2.y,lb2.z,ce,cnt); proc(b2.z,b2.w,lb2.w,ce,cnt);
            proc(a3.x,a3.y,lb3.x,ce,cnt); proc(a3.z,a3.w,lb3.y,ce,cnt);
            proc(b3.x,b3.y,lb3.z,ce,cnt); proc(b3.z,b3.w,lb3.w,ce,cnt);
        }
    } else {
        // tail block (unused for B = 2^24): per-chunk guards
        for (int k = 0; k < GROUPS * 4; ++k) {
            const int g = base + k * TPB + tid;
            if (g < nchunks) {
                const ix4 lb = lab4[g];
                const fx4 a = out4[2*g], b = out4[2*g+1];
                proc(a.x,a.y,lb.x,ce,cnt); proc(a.z,a.w,lb.y,ce,cnt);
                proc(b.x,b.y,lb.z,ce,cnt); proc(b.z,b.w,lb.w,ce,cnt);
            }
        }
    }

    // wave (64-lane) shuffle reduction
    #pragma unroll
    for (int off = 32; off > 0; off >>= 1) {
        ce  += __shfl_down(ce, off);
        cnt += __shfl_down(cnt, off);
    }

    __shared__ float              s_ce[TPB / 64];
    __shared__ unsigned long long s_cnt[TPB / 64];
    __shared__ int                s_last;
    const int wave = tid >> 6;
    const int lane = tid & 63;
    if (lane == 0) { s_ce[wave] = ce; s_cnt[wave] = cnt; }
    __syncthreads();

    if (tid == 0) {
        float bce = 0.0f;
        unsigned long long bc = 0ull;   // block totals <= 16384/field, fits 16 bits
        #pragma unroll
        for (int w = 0; w < TPB / 64; ++w) { bce += s_ce[w]; bc += s_cnt[w]; }
        // RELAXED agent atomics: plain sc1 (L2-bypass) stores, visible at the MALL.
        // No buffer_wbl2 / buffer_inv.
        __hip_atomic_store(&ce_part[blockIdx.x],
                           (unsigned long long)__double_as_longlong((double)bce),
                           __ATOMIC_RELAXED, __HIP_MEMORY_SCOPE_AGENT);
        __hip_atomic_store(&cnt_part[blockIdx.x], bc,
                           __ATOMIC_RELAXED, __HIP_MEMORY_SCOPE_AGENT);
        // Manual ordering: partial stores must complete (reach coherence point)
        // before this block's ticket increment is observable.
        asm volatile("s_waitcnt vmcnt(0)" ::: "memory");
        const unsigned int old = __hip_atomic_fetch_add(ticket, 1u,
                           __ATOMIC_RELAXED, __HIP_MEMORY_SCOPE_AGENT);
        s_last = (old == (unsigned int)(nparts - 1));
    }
    __syncthreads();
    if (!s_last) return;

    // ---- last block only: final cross-block reduction (replaces 2nd kernel) ----
    double ced = 0.0;
    // unpack BEFORE cross-block summation (16-bit fields would overflow)
    unsigned int q0 = 0, q1 = 0, q2 = 0, q3 = 0;
    for (int s = tid; s < nparts; s += TPB) {
        const unsigned long long cb = __hip_atomic_load(&ce_part[s],
                               __ATOMIC_RELAXED, __HIP_MEMORY_SCOPE_AGENT);
        ced += __longlong_as_double((long long)cb);
        const unsigned long long c  = __hip_atomic_load(&cnt_part[s],
                               __ATOMIC_RELAXED, __HIP_MEMORY_SCOPE_AGENT);
        q0 += (unsigned int)( c        & 0xffffull);  // TN
        q1 += (unsigned int)((c >> 16) & 0xffffull);  // FP
        q2 += (unsigned int)((c >> 32) & 0xffffull);  // FN
        q3 += (unsigned int)( c >> 48);               // TP
    }

    #pragma unroll
    for (int off = 32; off > 0; off >>= 1) {
        ced += __shfl_down(ced, off);
        q0  += __shfl_down(q0, off);
        q1  += __shfl_down(q1, off);
        q2  += __shfl_down(q2, off);
        q3  += __shfl_down(q3, off);
    }

    __shared__ double       f_ce[TPB / 64];
    __shared__ unsigned int f_q[4][TPB / 64];
    if (lane == 0) {
        f_ce[wave] = ced;
        f_q[0][wave] = q0; f_q[1][wave] = q1; f_q[2][wave] = q2; f_q[3][wave] = q3;
    }
    __syncthreads();

    if (tid == 0) {
        double ceT = 0.0;
        unsigned int TNu = 0, FPu = 0, FNu = 0, TPu = 0;
        #pragma unroll
        for (int w = 0; w < TPB / 64; ++w) {
            ceT += f_ce[w];
            TNu += f_q[0][w]; FPu += f_q[1][w]; FNu += f_q[2][w]; TPu += f_q[3][w];
        }
        const double TN = (double)TNu, FP = (double)FPu,
                     FN = (double)FNu, TP = (double)TPu;
        const double invB = 1.0 / (double)B;
        const bool nonzero = (TP > 0.0) && (TN > 0.0) && (FP > 0.0) && (FN > 0.0);
        const double ratio = (TP / fmax(TP + FN, 1.0)) * (FP / fmax(FP + TN, 1.0));
        const double coeff = nonzero ? (-0.5 * log(sqrt(fmax(ratio, 1e-30)))) : 0.5;
        // N_CLASSES=2: M[pred,label]==1 only when pred=0 & label=1 => sum(CS) == FN
        out[0] = (float)(ceT * invB + coeff * FN * invB);
    }
}

extern "C" void kernel_launch(void* const* d_in, const int* in_sizes, int n_in,
                              void* d_out, int out_size, void* d_ws, size_t ws_size,
                              hipStream_t stream) {
    const float* outputs = (const float*)d_in[0];
    const int*   labels  = (const int*)d_in[1];
    const int B = in_sizes[1];

    const int nchunks = B / 4;                         // B = 2^24 -> 4M chunks
    const int nparts  = (nchunks + CPB - 1) / CPB;     // 1024

    unsigned int*       ticket   = (unsigned int*)d_ws;
    unsigned long long* ce_part  = (unsigned long long*)((char*)d_ws + 256);
    unsigned long long* cnt_part = ce_part + nparts;

    // ws is poisoned by the harness each iteration — ticket must start at 0.
    hipMemsetAsync(d_ws, 0, 64, stream);

    detloss_fused<<<nparts, TPB, 0, stream>>>(
        (const fx4*)outputs, (const ix4*)labels,
        ticket, ce_part, cnt_part, (float*)d_out, B, nchunks, nparts);
}

// Round 3
// 218.681 us; speedup vs baseline: 3.2919x; 1.0007x over previous
//
#include <hip/hip_runtime.h>
#include <math.h>

#define TPB 256
#define GROUPS 4                         // 4 x (4 int4-chunks/thread) groups
#define CPB (TPB * 4 * GROUPS)           // 4096 chunks per block -> 1024 blocks
#define MAX_PARTS 8192                   // headroom; B=2^24 -> nparts=1024

typedef float fx4 __attribute__((ext_vector_type(4)));
typedef int   ix4 __attribute__((ext_vector_type(4)));

// State lives in module .bss (zero-initialized at load, NOT poisoned by the
// harness's 512MiB ws fills) -> no per-iteration memset dispatch needed.
//   g_ticket : last-block election counter. The WINNING block resets it to 0
//              before exiting, so every subsequent graph replay sees 0 again.
//              (Stream order serializes iterations; no overlap possible.)
//   g_ce/g_cnt : per-block partials. No init needed: every block writes its
//              slot before any block reads it (ordered by ticket + vmcnt(0)).
//
// MEMORY-MODEL NOTE (round-1 post-mortem): agent-scope RELEASE/ACQUIRE on gfx950
// lower to buffer_wbl2 / buffer_inv (whole-L2 writeback/invalidate) because
// per-XCD L2s are not coherent; 4096 of those serialized the machine (548us @
// 2.4% BW). Therefore RELAXED-only atomics (plain sc1 ops, visible at the MALL,
// no cache maintenance) + inline-asm s_waitcnt vmcnt(0) for store->ticket order.

__device__ unsigned int       g_ticket;            // .bss => 0 at load
__device__ unsigned long long g_ce[MAX_PARTS];     // double bits
__device__ unsigned long long g_cnt[MAX_PARTS];    // 4 x 16-bit packed fields

__device__ __forceinline__ void proc(float o0, float o1, int l,
                                     float& ce, unsigned long long& cnt) {
    // d = o0-o1; pred = (d<0); ce += softplus(l? d : -d)
    const float d = o0 - o1;
    ce += fmaxf(l ? d : -d, 0.0f) + __logf(1.0f + __expf(-fabsf(d)));
    cnt += 1ull << ((((l << 1) | (d < 0.0f ? 1 : 0))) << 4);  // field = label*2+pred
}

__global__ __launch_bounds__(TPB) void detloss_fused(
    const fx4* __restrict__ out4,   // outputs as float4 (2 elements each)
    const ix4* __restrict__ lab4,   // labels as int4 (4 elements each)
    float* __restrict__ out,
    int B, int nchunks, int nparts)
{
    float ce = 0.0f;
    unsigned long long cnt = 0ull;  // 4 x 16-bit fields; <=64/field/thread, <=16384/block
    const int tid  = threadIdx.x;
    const int base = blockIdx.x * CPB;

    if (base + CPB <= nchunks) {
        #pragma unroll
        for (int grp = 0; grp < GROUPS; ++grp) {
            const int g0 = base + grp * (TPB * 4) + tid;
            const int g1 = g0 + TPB, g2 = g1 + TPB, g3 = g2 + TPB;
            // 12 loads issued up front, nontemporal (read-once stream)
            const ix4 lb0 = __builtin_nontemporal_load(lab4 + g0);
            const ix4 lb1 = __builtin_nontemporal_load(lab4 + g1);
            const ix4 lb2 = __builtin_nontemporal_load(lab4 + g2);
            const ix4 lb3 = __builtin_nontemporal_load(lab4 + g3);
            const fx4 a0 = __builtin_nontemporal_load(out4 + 2*g0);
            const fx4 b0 = __builtin_nontemporal_load(out4 + 2*g0 + 1);
            const fx4 a1 = __builtin_nontemporal_load(out4 + 2*g1);
            const fx4 b1 = __builtin_nontemporal_load(out4 + 2*g1 + 1);
            const fx4 a2 = __builtin_nontemporal_load(out4 + 2*g2);
            const fx4 b2 = __builtin_nontemporal_load(out4 + 2*g2 + 1);
            const fx4 a3 = __builtin_nontemporal_load(out4 + 2*g3);
            const fx4 b3 = __builtin_nontemporal_load(out4 + 2*g3 + 1);

            proc(a0.x,a0.y,lb0.x,ce,cnt); proc(a0.z,a0.w,lb0.y,ce,cnt);
            proc(b0.x,b0.y,lb0.z,ce,cnt); proc(b0.z,b0.w,lb0.w,ce,cnt);
            proc(a1.x,a1.y,lb1.x,ce,cnt); proc(a1.z,a1.w,lb1.y,ce,cnt);
            proc(b1.x,b1.y,lb1.z,ce,cnt); proc(b1.z,b1.w,lb1.w,ce,cnt);
            proc(a2.x,a2.y,lb2.x,ce,cnt); proc(a2.z,a2.w,lb2.y,ce,cnt);
            proc(b2.x,b2.y,lb2.z,ce,cnt); proc(b2.z,b2.w,lb2.w,ce,cnt);
            proc(a3.x,a3.y,lb3.x,ce,cnt); proc(a3.z,a3.w,lb3.y,ce,cnt);
            proc(b3.x,b3.y,lb3.z,ce,cnt); proc(b3.z,b3.w,lb3.w,ce,cnt);
        }
    } else {
        // tail block (unused for B = 2^24): per-chunk guards
        for (int k = 0; k < GROUPS * 4; ++k) {
            const int g = base + k * TPB + tid;
            if (g < nchunks) {
                const ix4 lb = lab4[g];
                const fx4 a = out4[2*g], b = out4[2*g+1];
                proc(a.x,a.y,lb.x,ce,cnt); proc(a.z,a.w,lb.y,ce,cnt);
                proc(b.x,b.y,lb.z,ce,cnt); proc(b.z,b.w,lb.w,ce,cnt);
            }
        }
    }

    // wave (64-lane) shuffle reduction
    #pragma unroll
    for (int off = 32; off > 0; off >>= 1) {
        ce  += __shfl_down(ce, off);
        cnt += __shfl_down(cnt, off);
    }

    __shared__ float              s_ce[TPB / 64];
    __shared__ unsigned long long s_cnt[TPB / 64];
    __shared__ int                s_last;
    const int wave = tid >> 6;
    const int lane = tid & 63;
    if (lane == 0) { s_ce[wave] = ce; s_cnt[wave] = cnt; }
    __syncthreads();

    if (tid == 0) {
        float bce = 0.0f;
        unsigned long long bc = 0ull;   // block totals <= 16384/field, fits 16 bits
        #pragma unroll
        for (int w = 0; w < TPB / 64; ++w) { bce += s_ce[w]; bc += s_cnt[w]; }
        // RELAXED agent atomics: plain sc1 (L2-bypass) ops, visible at the MALL.
        // No buffer_wbl2 / buffer_inv.
        __hip_atomic_store(&g_ce[blockIdx.x],
                           (unsigned long long)__double_as_longlong((double)bce),
                           __ATOMIC_RELAXED, __HIP_MEMORY_SCOPE_AGENT);
        __hip_atomic_store(&g_cnt[blockIdx.x], bc,
                           __ATOMIC_RELAXED, __HIP_MEMORY_SCOPE_AGENT);
        // Manual ordering: partial stores must reach the coherence point before
        // this block's ticket increment is observable.
        asm volatile("s_waitcnt vmcnt(0)" ::: "memory");
        const unsigned int old = __hip_atomic_fetch_add(&g_ticket, 1u,
                           __ATOMIC_RELAXED, __HIP_MEMORY_SCOPE_AGENT);
        const int is_last = (old == (unsigned int)(nparts - 1));
        if (is_last) {
            // re-arm for the next graph replay (no other block touches the
            // ticket after its single fetch_add; iterations are stream-ordered)
            __hip_atomic_store(&g_ticket, 0u,
                               __ATOMIC_RELAXED, __HIP_MEMORY_SCOPE_AGENT);
        }
        s_last = is_last;
    }
    __syncthreads();
    if (!s_last) return;

    // ---- last block only: final cross-block reduction (replaces 2nd kernel) ----
    double ced = 0.0;
    // unpack BEFORE cross-block summation (16-bit fields would overflow)
    unsigned int q0 = 0, q1 = 0, q2 = 0, q3 = 0;
    for (int s = tid; s < nparts; s += TPB) {
        const unsigned long long cb = __hip_atomic_load(&g_ce[s],
                               __ATOMIC_RELAXED, __HIP_MEMORY_SCOPE_AGENT);
        ced += __longlong_as_double((long long)cb);
        const unsigned long long c  = __hip_atomic_load(&g_cnt[s],
                               __ATOMIC_RELAXED, __HIP_MEMORY_SCOPE_AGENT);
        q0 += (unsigned int)( c        & 0xffffull);  // TN
        q1 += (unsigned int)((c >> 16) & 0xffffull);  // FP
        q2 += (unsigned int)((c >> 32) & 0xffffull);  // FN
        q3 += (unsigned int)( c >> 48);               // TP
    }

    #pragma unroll
    for (int off = 32; off > 0; off >>= 1) {
        ced += __shfl_down(ced, off);
        q0  += __shfl_down(q0, off);
        q1  += __shfl_down(q1, off);
        q2  += __shfl_down(q2, off);
        q3  += __shfl_down(q3, off);
    }

    __shared__ double       f_ce[TPB / 64];
    __shared__ unsigned int f_q[4][TPB / 64];
    if (lane == 0) {
        f_ce[wave] = ced;
        f_q[0][wave] = q0; f_q[1][wave] = q1; f_q[2][wave] = q2; f_q[3][wave] = q3;
    }
    __syncthreads();

    if (tid == 0) {
        double ceT = 0.0;
        unsigned int TNu = 0, FPu = 0, FNu = 0, TPu = 0;
        #pragma unroll
        for (int w = 0; w < TPB / 64; ++w) {
            ceT += f_ce[w];
            TNu += f_q[0][w]; FPu += f_q[1][w]; FNu += f_q[2][w]; TPu += f_q[3][w];
        }
        const double TN = (double)TNu, FP = (double)FPu,
                     FN = (double)FNu, TP = (double)TPu;
        const double invB = 1.0 / (double)B;
        const bool nonzero = (TP > 0.0) && (TN > 0.0) && (FP > 0.0) && (FN > 0.0);
        const double ratio = (TP / fmax(TP + FN, 1.0)) * (FP / fmax(FP + TN, 1.0));
        const double coeff = nonzero ? (-0.5 * log(sqrt(fmax(ratio, 1e-30)))) : 0.5;
        // N_CLASSES=2: M[pred,label]==1 only when pred=0 & label=1 => sum(CS) == FN
        out[0] = (float)(ceT * invB + coeff * FN * invB);
    }
}

extern "C" void kernel_launch(void* const* d_in, const int* in_sizes, int n_in,
                              void* d_out, int out_size, void* d_ws, size_t ws_size,
                              hipStream_t stream) {
    const float* outputs = (const float*)d_in[0];
    const int*   labels  = (const int*)d_in[1];
    const int B = in_sizes[1];

    const int nchunks = B / 4;                         // B = 2^24 -> 4M chunks
    const int nparts  = (nchunks + CPB - 1) / CPB;     // 1024 (<= MAX_PARTS)

    detloss_fused<<<nparts, TPB, 0, stream>>>(
        (const fx4*)outputs, (const ix4*)labels,
        (float*)d_out, B, nchunks, nparts);
}